// Round 4
// baseline (464.065 us; speedup 1.0000x reference)
//
#include <hip/hip_runtime.h>
#include <hip/hip_bf16.h>
#include <math.h>

#define IMG 224
#define PIX (IMG*IMG)   // 50176
#define B_ 32
#define E_ 512
#define N_ 4096
#define SV_BLOCKS 256
#define SC_ ((float)(512.0/224.0))
#define RPB 16          // rows per stats block
#define NCHUNK 32       // E_/RPB

typedef __attribute__((ext_vector_type(8))) short bf16x8;
typedef __attribute__((ext_vector_type(4))) float f32x4;

__device__ inline unsigned short f2bf(float f){
  unsigned u = __float_as_uint(f);
  unsigned r = (u + 0x7FFFu + ((u >> 16) & 1u)) >> 16;  // RNE
  return (unsigned short)r;
}

// ---------- fused: row stats + column partials + inline y emission ----------
// grid = B*32. Block: batch b, source rows e0..e0+15 (reads e0..e0+16).
// Thread t owns columns {1024k + 4t + j : k<4, j<4} — lane-stride-16B loads
// (fully coalesced 1KB/wave/instr). y row i emitted when both stencil rows'
// stats are ready; r0(i) in [e0, e0+15] owned by this block.
__global__ void __launch_bounds__(256) stats_y(const float* __restrict__ x,
                                               float* __restrict__ meanv,
                                               float* __restrict__ colpart,
                                               ushort* __restrict__ y){
  int b = blockIdx.x >> 5, chunk = blockIdx.x & 31;
  int e0 = chunk << 4;
  int t = threadIdx.x;
  __shared__ short sInv[512];   // src row r0 -> output row i (or -1)
  __shared__ float sW[224];     // interp weight per output row
  __shared__ float red[2][16];  // parity-buffered reduction slab
  sInv[t] = -1; sInv[t + 256] = -1;
  __syncthreads();
  if (t < 224){
    float r = fmaxf(((float)t + 0.5f) * SC_ - 0.5f, 0.f);
    int r0 = min((int)r, E_ - 1);
    sW[t] = r - (float)r0;
    sInv[r0] = (short)t;        // scale > 2 => at most one i per r0
  }
  __syncthreads();

  float cur[16], prev[16], nxt[16], csum[16];
  #pragma unroll
  for (int j = 0; j < 16; j++){ csum[j] = 0.f; prev[j] = 0.f; }
  const float4* row0 = (const float4*)(x + ((size_t)b * E_ + e0) * N_);
  #pragma unroll
  for (int k = 0; k < 4; k++) *(float4*)(cur + 4 * k) = row0[t + 256 * k];
  float pmu = 0.f, prn = 0.f;

  for (int idx = 0; idx <= RPB; idx++){
    int e = e0 + idx;
    if (e >= E_) break;
    bool hasNext = (idx < RPB) && (e + 1 < E_);
    if (hasNext){
      const float4* nr = (const float4*)(x + ((size_t)b * E_ + e + 1) * N_);
      #pragma unroll
      for (int k = 0; k < 4; k++) *(float4*)(nxt + 4 * k) = nr[t + 256 * k];
    }
    float s = 0.f, ss = 0.f;
    #pragma unroll
    for (int j = 0; j < 16; j++){ s += cur[j]; ss += cur[j] * cur[j]; }
    #pragma unroll
    for (int o = 32; o; o >>= 1){ s += __shfl_down(s, o); ss += __shfl_down(ss, o); }
    int wv = t >> 6, ln = t & 63, p = idx & 1;
    if (ln == 0){ red[p][wv] = s; red[p][8 + wv] = ss; }
    __syncthreads();    // single barrier per row (parity buffer handles reuse)
    float S  = red[p][0] + red[p][1] + red[p][2] + red[p][3];
    float SS = red[p][8] + red[p][9] + red[p][10] + red[p][11];
    float mu = S * (1.f / N_);
    float var = fmaxf(SS - S * S * (1.f / N_), 0.f);
    float rn = 1.f / (sqrtf(var) + 1e-8f);
    if (idx < RPB){
      #pragma unroll
      for (int j = 0; j < 16; j++) csum[j] += cur[j];
      if (t == 0) meanv[b * E_ + e] = mu;
    }
    if (idx >= 1){
      int i = sInv[e - 1];
      if (i >= 0){
        float w = sW[i];
        float a0 = (1.f - w) * prn, a1 = w * rn;
        float cc = -(a0 * pmu + a1 * mu);
        ushort* yo = y + ((size_t)b * IMG + i) * N_;
        #pragma unroll
        for (int k = 0; k < 4; k++){
          union { ushort u[4]; int2 v; } pk;
          #pragma unroll
          for (int j = 0; j < 4; j++)
            pk.u[j] = f2bf(a0 * prev[4*k+j] + a1 * cur[4*k+j] + cc);
          *(int2*)(yo + 1024 * k + 4 * t) = pk.v;
        }
      }
    }
    pmu = mu; prn = rn;
    #pragma unroll
    for (int j = 0; j < 16; j++){ prev[j] = cur[j]; if (hasNext) cur[j] = nxt[j]; }
  }
  float* cp = colpart + ((size_t)(b * NCHUNK + chunk)) * N_;
  #pragma unroll
  for (int k = 0; k < 4; k++) *(float4*)(cp + 1024 * k + 4 * t) = *(float4*)(csum + 4 * k);
}

// colmean[b][n] = (1/E) * sum of 32 partials
__global__ void __launch_bounds__(256) col_finalize(const float* __restrict__ colpart,
                                                    float* __restrict__ colmean){
  int b = blockIdx.x >> 4;
  int n = ((blockIdx.x & 15) << 8) + threadIdx.x;
  float s = 0.f;
  #pragma unroll
  for (int c = 0; c < NCHUNK; c++) s += colpart[((size_t)(b * NCHUNK + c)) * N_ + n];
  colmean[b * N_ + n] = s * (1.f / E_);
}

// ---------------- small views (temporal + spatial) ------------------------
__device__ inline float grid_val(const float* v, int gs, int n, int r, int c){
  int idx = r * gs + c;
  return (idx < n) ? v[idx] : 0.f;
}
__device__ inline float bilin(const float* v, int gs, int n, int i, int j){
  float sc = (float)((double)gs / 224.0);
  float r = fmaxf(((float)i + 0.5f) * sc - 0.5f, 0.f);
  float c = fmaxf(((float)j + 0.5f) * sc - 0.5f, 0.f);
  int r0 = min((int)r, gs - 1), c0 = min((int)c, gs - 1);
  int r1 = min(r0 + 1, gs - 1), c1 = min(c0 + 1, gs - 1);
  float wr = r - (float)r0, wc = c - (float)c0;
  float v00 = grid_val(v, gs, n, r0, c0), v10 = grid_val(v, gs, n, r1, c0);
  float v01 = grid_val(v, gs, n, r0, c1), v11 = grid_val(v, gs, n, r1, c1);
  float ra = v00 * (1.f - wr) + v10 * wr;
  float rb = v01 * (1.f - wr) + v11 * wr;
  return ra * (1.f - wc) + rb * wc;
}

__global__ void __launch_bounds__(256) small_views(const float* __restrict__ meanv,
                                                   const float* __restrict__ colmean,
                                                   float* __restrict__ out,
                                                   float* __restrict__ scr){
  float tmn = INFINITY, tmx = -INFINITY, smn = INFINITY, smx = -INFINITY;
  for (int g = blockIdx.x * 256 + threadIdx.x; g < B_ * PIX; g += SV_BLOCKS * 256){
    int b = g / PIX, p = g - b * PIX;
    int i = p / IMG, j = p - i * IMG;
    float tv = bilin(meanv   + b * E_, 23, E_, i, j);
    float sv = bilin(colmean + b * N_, 64, N_, i, j);
    out[((size_t)b * 3 + 0) * PIX + p] = tv;
    out[((size_t)b * 3 + 1) * PIX + p] = sv;
    tmn = fminf(tmn, tv); tmx = fmaxf(tmx, tv);
    smn = fminf(smn, sv); smx = fmaxf(smx, sv);
  }
  #pragma unroll
  for (int o = 32; o; o >>= 1){
    tmn = fminf(tmn, __shfl_down(tmn, o)); tmx = fmaxf(tmx, __shfl_down(tmx, o));
    smn = fminf(smn, __shfl_down(smn, o)); smx = fmaxf(smx, __shfl_down(smx, o));
  }
  __shared__ float red[4][4];
  int wv = threadIdx.x >> 6, ln = threadIdx.x & 63;
  if (ln == 0){ red[wv][0] = tmn; red[wv][1] = tmx; red[wv][2] = smn; red[wv][3] = smx; }
  __syncthreads();
  if (threadIdx.x == 0){
    scr[blockIdx.x * 4 + 0] = fminf(fminf(red[0][0], red[1][0]), fminf(red[2][0], red[3][0]));
    scr[blockIdx.x * 4 + 1] = fmaxf(fmaxf(red[0][1], red[1][1]), fmaxf(red[2][1], red[3][1]));
    scr[blockIdx.x * 4 + 2] = fminf(fminf(red[0][2], red[1][2]), fminf(red[2][2], red[3][2]));
    scr[blockIdx.x * 4 + 3] = fmaxf(fmaxf(red[0][3], red[1][3]), fmaxf(red[2][3], red[3][3]));
  }
}

// ---------------- correlation GEMM: C = y*y^T, symmetric tiles only --------
#define LDSTR 72
__global__ void __launch_bounds__(256) corr_gemm(const ushort* __restrict__ y,
                                                 float* __restrict__ out,
                                                 float* __restrict__ scr){
  const int TI[10] = {0,0,0,0,1,1,1,2,2,3};
  const int TJ[10] = {0,1,2,3,1,2,3,2,3,3};
  int b = blockIdx.x / 10;
  int tile = blockIdx.x - b * 10;
  int ti = TI[tile], tj = TJ[tile];
  bool diag = (ti == tj);
  const ushort* yb = y + (size_t)b * IMG * N_;
  __shared__ ushort lA[64 * LDSTR];
  __shared__ ushort lB[64 * LDSTR];
  int t = threadIdx.x;
  int wv = t >> 6, ln = t & 63;
  int wm = wv & 1, wn = wv >> 1;
  int quad = ln >> 4, l16 = ln & 15;
  f32x4 acc[2][2] = {};
  int s = t & 7, r2 = t >> 3;
  int rA0 = min(ti * 64 + r2,      223), rA1 = min(ti * 64 + r2 + 32, 223);
  int rB0 = min(tj * 64 + r2,      223), rB1 = min(tj * 64 + r2 + 32, 223);
  for (int k0 = 0; k0 < N_; k0 += 64){
    int4 a0 = *(const int4*)(yb + (size_t)rA0 * N_ + k0 + s * 8);
    int4 a1 = *(const int4*)(yb + (size_t)rA1 * N_ + k0 + s * 8);
    int4 b0v = *(const int4*)(yb + (size_t)rB0 * N_ + k0 + s * 8);
    int4 b1v = *(const int4*)(yb + (size_t)rB1 * N_ + k0 + s * 8);
    __syncthreads();
    *(int4*)(lA + r2 * LDSTR + s * 8)        = a0;
    *(int4*)(lA + (r2 + 32) * LDSTR + s * 8) = a1;
    *(int4*)(lB + r2 * LDSTR + s * 8)        = b0v;
    *(int4*)(lB + (r2 + 32) * LDSTR + s * 8) = b1v;
    __syncthreads();
    #pragma unroll
    for (int kk = 0; kk < 2; kk++){
      bf16x8 af0 = *(const bf16x8*)(lA + (wm * 32 + l16)      * LDSTR + kk * 32 + quad * 8);
      bf16x8 af1 = *(const bf16x8*)(lA + (wm * 32 + 16 + l16) * LDSTR + kk * 32 + quad * 8);
      bf16x8 bf0 = *(const bf16x8*)(lB + (wn * 32 + l16)      * LDSTR + kk * 32 + quad * 8);
      bf16x8 bf1 = *(const bf16x8*)(lB + (wn * 32 + 16 + l16) * LDSTR + kk * 32 + quad * 8);
      acc[0][0] = __builtin_amdgcn_mfma_f32_16x16x32_bf16(af0, bf0, acc[0][0], 0, 0, 0);
      acc[0][1] = __builtin_amdgcn_mfma_f32_16x16x32_bf16(af0, bf1, acc[0][1], 0, 0, 0);
      acc[1][0] = __builtin_amdgcn_mfma_f32_16x16x32_bf16(af1, bf0, acc[1][0], 0, 0, 0);
      acc[1][1] = __builtin_amdgcn_mfma_f32_16x16x32_bf16(af1, bf1, acc[1][1], 0, 0, 0);
    }
  }
  float mn = INFINITY, mx = -INFINITY;
  float* ov = out + ((size_t)b * 3 + 2) * PIX;
  #pragma unroll
  for (int im = 0; im < 2; im++)
    #pragma unroll
    for (int in = 0; in < 2; in++){
      int gi0 = ti * 64 + wm * 32 + im * 16 + quad * 4;
      int gj  = tj * 64 + wn * 32 + in * 16 + l16;
      #pragma unroll
      for (int rg = 0; rg < 4; rg++){
        int gi = gi0 + rg;
        if (gi < IMG && gj < IMG){
          float v = acc[im][in][rg];
          ov[gi * IMG + gj] = v;
          mn = fminf(mn, v); mx = fmaxf(mx, v);
        }
      }
      if (!diag && gj < IMG && gi0 < IMG){   // mirrored tile, packed store
        float4 tv;
        tv.x = acc[im][in][0]; tv.y = acc[im][in][1];
        tv.z = acc[im][in][2]; tv.w = acc[im][in][3];
        *(float4*)(ov + gj * IMG + gi0) = tv;
      }
    }
  #pragma unroll
  for (int o = 32; o; o >>= 1){
    mn = fminf(mn, __shfl_down(mn, o)); mx = fmaxf(mx, __shfl_down(mx, o));
  }
  __shared__ float red[4][2];
  if (ln == 0){ red[wv][0] = mn; red[wv][1] = mx; }
  __syncthreads();
  if (t == 0){
    scr[(b * 10 + tile) * 2 + 0] = fminf(fminf(red[0][0], red[1][0]), fminf(red[2][0], red[3][0]));
    scr[(b * 10 + tile) * 2 + 1] = fmaxf(fmaxf(red[0][1], red[1][1]), fmaxf(red[2][1], red[3][1]));
  }
}

// ---------------- final minmax reduce + normalize --------------------------
__global__ void __launch_bounds__(256) reduce_slots(const float* __restrict__ sv_scr,
                                                    const float* __restrict__ corr_scr,
                                                    float* __restrict__ slots){
  int t = threadIdx.x;
  float tmn = sv_scr[4*t+0], tmx = sv_scr[4*t+1];
  float smn = sv_scr[4*t+2], smx = sv_scr[4*t+3];
  float cmn = INFINITY, cmx = -INFINITY;
  for (int idx = t; idx < B_ * 10; idx += 256){
    cmn = fminf(cmn, corr_scr[2*idx]);
    cmx = fmaxf(cmx, corr_scr[2*idx+1]);
  }
  #pragma unroll
  for (int o = 32; o; o >>= 1){
    tmn = fminf(tmn, __shfl_down(tmn, o)); tmx = fmaxf(tmx, __shfl_down(tmx, o));
    smn = fminf(smn, __shfl_down(smn, o)); smx = fmaxf(smx, __shfl_down(smx, o));
    cmn = fminf(cmn, __shfl_down(cmn, o)); cmx = fmaxf(cmx, __shfl_down(cmx, o));
  }
  __shared__ float red[4][6];
  int wv = t >> 6, ln = t & 63;
  if (ln == 0){
    red[wv][0]=tmn; red[wv][1]=tmx; red[wv][2]=smn;
    red[wv][3]=smx; red[wv][4]=cmn; red[wv][5]=cmx;
  }
  __syncthreads();
  if (t == 0){
    slots[0] = fminf(fminf(red[0][0],red[1][0]), fminf(red[2][0],red[3][0]));
    slots[1] = fmaxf(fmaxf(red[0][1],red[1][1]), fmaxf(red[2][1],red[3][1]));
    slots[2] = fminf(fminf(red[0][2],red[1][2]), fminf(red[2][2],red[3][2]));
    slots[3] = fmaxf(fmaxf(red[0][3],red[1][3]), fmaxf(red[2][3],red[3][3]));
    slots[4] = fminf(fminf(red[0][4],red[1][4]), fminf(red[2][4],red[3][4]));
    slots[5] = fmaxf(fmaxf(red[0][5],red[1][5]), fmaxf(red[2][5],red[3][5]));
  }
}

__global__ void __launch_bounds__(256) normalize_k(float* __restrict__ out,
                                                   const float* __restrict__ slots){
  int g = blockIdx.x * 256 + threadIdx.x;
  if (g >= B_ * 3 * PIX) return;
  int view = (g / PIX) % 3;  // uniform per block (PIX % 256 == 0)
  float mn = slots[2 * view];
  float mx = slots[2 * view + 1];
  float d = mx - mn;
  float v = out[g];
  out[g] = (d < 1e-8f) ? 0.f : (v - mn) / (d + 1e-8f);
}

extern "C" void kernel_launch(void* const* d_in, const int* in_sizes, int n_in,
                              void* d_out, int out_size, void* d_ws, size_t ws_size,
                              hipStream_t stream){
  const float* x = (const float*)d_in[0];
  float* out = (float*)d_out;
  char* ws = (char*)d_ws;
  float* slots    = (float*)(ws + 0);                     // 6 f (pad 256 B)
  float* meanv    = (float*)(ws + 256);                   // B*E f
  float* colmean  = meanv + B_ * E_;                      // B*N f
  float* colpart  = colmean + B_ * N_;                    // B*32*N f (16 MB)
  float* sv_scr   = colpart + (size_t)B_ * NCHUNK * N_;   // SV_BLOCKS*4 f
  float* corr_scr = sv_scr + SV_BLOCKS * 4;               // 640 f
  size_t y_off = ((size_t)((char*)(corr_scr + B_ * 10 * 2) - ws) + 255) & ~(size_t)255;
  ushort* y = (ushort*)(ws + y_off);                      // B*224*4096 bf16 (58.7 MB)

  hipLaunchKernelGGL(stats_y, dim3(B_ * NCHUNK), dim3(256), 0, stream,
                     x, meanv, colpart, y);
  hipLaunchKernelGGL(col_finalize, dim3(B_ * 16), dim3(256), 0, stream,
                     colpart, colmean);
  hipLaunchKernelGGL(small_views, dim3(SV_BLOCKS), dim3(256), 0, stream,
                     meanv, colmean, out, sv_scr);
  hipLaunchKernelGGL(corr_gemm, dim3(B_ * 10), dim3(256), 0, stream,
                     y, out, corr_scr);
  hipLaunchKernelGGL(reduce_slots, dim3(1), dim3(256), 0, stream,
                     sv_scr, corr_scr, slots);
  hipLaunchKernelGGL(normalize_k, dim3((B_ * 3 * PIX + 255) / 256), dim3(256), 0, stream,
                     out, slots);
}

// Round 5
// 450.772 us; speedup vs baseline: 1.0295x; 1.0295x over previous
//
#include <hip/hip_runtime.h>
#include <hip/hip_bf16.h>
#include <math.h>

#define IMG 224
#define PIX (IMG*IMG)   // 50176
#define B_ 32
#define E_ 512
#define N_ 4096
#define SV_BLOCKS 256
#define SC_ ((float)(512.0/224.0))
#define RPB 16          // rows per stats block
#define NCHUNK 32       // E_/RPB
#define KSPLIT 4
#define KLEN (N_/KSPLIT)  // 1024
#define NTILE 10          // symmetric 64x64 tiles of 224x224

typedef __attribute__((ext_vector_type(8))) short bf16x8;
typedef __attribute__((ext_vector_type(4))) float f32x4;

__device__ inline unsigned short f2bf(float f){
  unsigned u = __float_as_uint(f);
  unsigned r = (u + 0x7FFFu + ((u >> 16) & 1u)) >> 16;  // RNE
  return (unsigned short)r;
}

// ---------- fused: row stats + column partials + inline y emission ----------
__global__ void __launch_bounds__(256) stats_y(const float* __restrict__ x,
                                               float* __restrict__ meanv,
                                               float* __restrict__ colpart,
                                               ushort* __restrict__ y){
  int b = blockIdx.x >> 5, chunk = blockIdx.x & 31;
  int e0 = chunk << 4;
  int t = threadIdx.x;
  __shared__ short sInv[512];   // src row r0 -> output row i (or -1)
  __shared__ float sW[224];     // interp weight per output row
  __shared__ float red[2][16];  // parity-buffered reduction slab
  sInv[t] = -1; sInv[t + 256] = -1;
  __syncthreads();
  if (t < 224){
    float r = fmaxf(((float)t + 0.5f) * SC_ - 0.5f, 0.f);
    int r0 = min((int)r, E_ - 1);
    sW[t] = r - (float)r0;
    sInv[r0] = (short)t;        // scale > 2 => at most one i per r0
  }
  __syncthreads();

  float cur[16], prev[16], nxt[16], csum[16];
  #pragma unroll
  for (int j = 0; j < 16; j++){ csum[j] = 0.f; prev[j] = 0.f; }
  const float4* row0 = (const float4*)(x + ((size_t)b * E_ + e0) * N_);
  #pragma unroll
  for (int k = 0; k < 4; k++) *(float4*)(cur + 4 * k) = row0[t + 256 * k];
  float pmu = 0.f, prn = 0.f;

  for (int idx = 0; idx <= RPB; idx++){
    int e = e0 + idx;
    if (e >= E_) break;
    bool hasNext = (idx < RPB) && (e + 1 < E_);
    if (hasNext){
      const float4* nr = (const float4*)(x + ((size_t)b * E_ + e + 1) * N_);
      #pragma unroll
      for (int k = 0; k < 4; k++) *(float4*)(nxt + 4 * k) = nr[t + 256 * k];
    }
    float s = 0.f, ss = 0.f;
    #pragma unroll
    for (int j = 0; j < 16; j++){ s += cur[j]; ss += cur[j] * cur[j]; }
    #pragma unroll
    for (int o = 32; o; o >>= 1){ s += __shfl_down(s, o); ss += __shfl_down(ss, o); }
    int wv = t >> 6, ln = t & 63, p = idx & 1;
    if (ln == 0){ red[p][wv] = s; red[p][8 + wv] = ss; }
    __syncthreads();    // single barrier per row
    float S  = red[p][0] + red[p][1] + red[p][2] + red[p][3];
    float SS = red[p][8] + red[p][9] + red[p][10] + red[p][11];
    float mu = S * (1.f / N_);
    float var = fmaxf(SS - S * S * (1.f / N_), 0.f);
    float rn = 1.f / (sqrtf(var) + 1e-8f);
    if (idx < RPB){
      #pragma unroll
      for (int j = 0; j < 16; j++) csum[j] += cur[j];
      if (t == 0) meanv[b * E_ + e] = mu;
    }
    if (idx >= 1){
      int i = sInv[e - 1];
      if (i >= 0){
        float w = sW[i];
        float a0 = (1.f - w) * prn, a1 = w * rn;
        float cc = -(a0 * pmu + a1 * mu);
        ushort* yo = y + ((size_t)b * IMG + i) * N_;
        #pragma unroll
        for (int k = 0; k < 4; k++){
          union { ushort u[4]; int2 v; } pk;
          #pragma unroll
          for (int j = 0; j < 4; j++)
            pk.u[j] = f2bf(a0 * prev[4*k+j] + a1 * cur[4*k+j] + cc);
          *(int2*)(yo + 1024 * k + 4 * t) = pk.v;
        }
      }
    }
    pmu = mu; prn = rn;
    #pragma unroll
    for (int j = 0; j < 16; j++){ prev[j] = cur[j]; if (hasNext) cur[j] = nxt[j]; }
  }
  float* cp = colpart + ((size_t)(b * NCHUNK + chunk)) * N_;
  #pragma unroll
  for (int k = 0; k < 4; k++) *(float4*)(cp + 1024 * k + 4 * t) = *(float4*)(csum + 4 * k);
}

// colmean[b][n] = (1/E) * sum of 32 partials
__global__ void __launch_bounds__(256) col_finalize(const float* __restrict__ colpart,
                                                    float* __restrict__ colmean){
  int b = blockIdx.x >> 4;
  int n = ((blockIdx.x & 15) << 8) + threadIdx.x;
  float s = 0.f;
  #pragma unroll
  for (int c = 0; c < NCHUNK; c++) s += colpart[((size_t)(b * NCHUNK + c)) * N_ + n];
  colmean[b * N_ + n] = s * (1.f / E_);
}

// ---------------- small views (temporal + spatial) ------------------------
__device__ inline float grid_val(const float* v, int gs, int n, int r, int c){
  int idx = r * gs + c;
  return (idx < n) ? v[idx] : 0.f;
}
__device__ inline float bilin(const float* v, int gs, int n, int i, int j){
  float sc = (float)((double)gs / 224.0);
  float r = fmaxf(((float)i + 0.5f) * sc - 0.5f, 0.f);
  float c = fmaxf(((float)j + 0.5f) * sc - 0.5f, 0.f);
  int r0 = min((int)r, gs - 1), c0 = min((int)c, gs - 1);
  int r1 = min(r0 + 1, gs - 1), c1 = min(c0 + 1, gs - 1);
  float wr = r - (float)r0, wc = c - (float)c0;
  float v00 = grid_val(v, gs, n, r0, c0), v10 = grid_val(v, gs, n, r1, c0);
  float v01 = grid_val(v, gs, n, r0, c1), v11 = grid_val(v, gs, n, r1, c1);
  float ra = v00 * (1.f - wr) + v10 * wr;
  float rb = v01 * (1.f - wr) + v11 * wr;
  return ra * (1.f - wc) + rb * wc;
}

__global__ void __launch_bounds__(256) small_views(const float* __restrict__ meanv,
                                                   const float* __restrict__ colmean,
                                                   float* __restrict__ out,
                                                   float* __restrict__ scr){
  float tmn = INFINITY, tmx = -INFINITY, smn = INFINITY, smx = -INFINITY;
  for (int g = blockIdx.x * 256 + threadIdx.x; g < B_ * PIX; g += SV_BLOCKS * 256){
    int b = g / PIX, p = g - b * PIX;
    int i = p / IMG, j = p - i * IMG;
    float tv = bilin(meanv   + b * E_, 23, E_, i, j);
    float sv = bilin(colmean + b * N_, 64, N_, i, j);
    out[((size_t)b * 3 + 0) * PIX + p] = tv;
    out[((size_t)b * 3 + 1) * PIX + p] = sv;
    tmn = fminf(tmn, tv); tmx = fmaxf(tmx, tv);
    smn = fminf(smn, sv); smx = fmaxf(smx, sv);
  }
  #pragma unroll
  for (int o = 32; o; o >>= 1){
    tmn = fminf(tmn, __shfl_down(tmn, o)); tmx = fmaxf(tmx, __shfl_down(tmx, o));
    smn = fminf(smn, __shfl_down(smn, o)); smx = fmaxf(smx, __shfl_down(smx, o));
  }
  __shared__ float red[4][4];
  int wv = threadIdx.x >> 6, ln = threadIdx.x & 63;
  if (ln == 0){ red[wv][0] = tmn; red[wv][1] = tmx; red[wv][2] = smn; red[wv][3] = smx; }
  __syncthreads();
  if (threadIdx.x == 0){
    scr[blockIdx.x * 4 + 0] = fminf(fminf(red[0][0], red[1][0]), fminf(red[2][0], red[3][0]));
    scr[blockIdx.x * 4 + 1] = fmaxf(fmaxf(red[0][1], red[1][1]), fmaxf(red[2][1], red[3][1]));
    scr[blockIdx.x * 4 + 2] = fminf(fminf(red[0][2], red[1][2]), fminf(red[2][2], red[3][2]));
    scr[blockIdx.x * 4 + 3] = fmaxf(fmaxf(red[0][3], red[1][3]), fmaxf(red[2][3], red[3][3]));
  }
}

// ---------------- correlation GEMM: split-K partials -----------------------
// grid = KSPLIT * B * NTILE. Block (ks, b, tile) computes 64x64 partial over
// K in [ks*KLEN, (ks+1)*KLEN). Output thread-packed (t*16) -> coalesced.
#define LDSTR 72
__device__ const int TI_[NTILE] = {0,0,0,0,1,1,1,2,2,3};
__device__ const int TJ_[NTILE] = {0,1,2,3,1,2,3,2,3,3};

__global__ void __launch_bounds__(256) corr_gemm_sk(const ushort* __restrict__ y,
                                                    float* __restrict__ partials){
  int bt = blockIdx.x % (B_ * NTILE);
  int ks = blockIdx.x / (B_ * NTILE);
  int b = bt / NTILE, tile = bt - b * NTILE;
  int ti = TI_[tile], tj = TJ_[tile];
  const ushort* yb = y + (size_t)b * IMG * N_ + (size_t)ks * KLEN;
  __shared__ ushort lA[64 * LDSTR];
  __shared__ ushort lB[64 * LDSTR];
  int t = threadIdx.x;
  int wv = t >> 6, ln = t & 63;
  int wm = wv & 1, wn = wv >> 1;
  int quad = ln >> 4, l16 = ln & 15;
  f32x4 acc[2][2] = {};
  int s = t & 7, r2 = t >> 3;
  int rA0 = min(ti * 64 + r2,      223), rA1 = min(ti * 64 + r2 + 32, 223);
  int rB0 = min(tj * 64 + r2,      223), rB1 = min(tj * 64 + r2 + 32, 223);
  for (int k0 = 0; k0 < KLEN; k0 += 64){
    int4 a0 = *(const int4*)(yb + (size_t)rA0 * N_ + k0 + s * 8);
    int4 a1 = *(const int4*)(yb + (size_t)rA1 * N_ + k0 + s * 8);
    int4 b0v = *(const int4*)(yb + (size_t)rB0 * N_ + k0 + s * 8);
    int4 b1v = *(const int4*)(yb + (size_t)rB1 * N_ + k0 + s * 8);
    __syncthreads();
    *(int4*)(lA + r2 * LDSTR + s * 8)        = a0;
    *(int4*)(lA + (r2 + 32) * LDSTR + s * 8) = a1;
    *(int4*)(lB + r2 * LDSTR + s * 8)        = b0v;
    *(int4*)(lB + (r2 + 32) * LDSTR + s * 8) = b1v;
    __syncthreads();
    #pragma unroll
    for (int kk = 0; kk < 2; kk++){
      bf16x8 af0 = *(const bf16x8*)(lA + (wm * 32 + l16)      * LDSTR + kk * 32 + quad * 8);
      bf16x8 af1 = *(const bf16x8*)(lA + (wm * 32 + 16 + l16) * LDSTR + kk * 32 + quad * 8);
      bf16x8 bf0 = *(const bf16x8*)(lB + (wn * 32 + l16)      * LDSTR + kk * 32 + quad * 8);
      bf16x8 bf1 = *(const bf16x8*)(lB + (wn * 32 + 16 + l16) * LDSTR + kk * 32 + quad * 8);
      acc[0][0] = __builtin_amdgcn_mfma_f32_16x16x32_bf16(af0, bf0, acc[0][0], 0, 0, 0);
      acc[0][1] = __builtin_amdgcn_mfma_f32_16x16x32_bf16(af0, bf1, acc[0][1], 0, 0, 0);
      acc[1][0] = __builtin_amdgcn_mfma_f32_16x16x32_bf16(af1, bf0, acc[1][0], 0, 0, 0);
      acc[1][1] = __builtin_amdgcn_mfma_f32_16x16x32_bf16(af1, bf1, acc[1][1], 0, 0, 0);
    }
  }
  float* pp = partials + ((size_t)ks * (B_ * NTILE) + bt) * 4096 + t * 16;
  #pragma unroll
  for (int im = 0; im < 2; im++)
    #pragma unroll
    for (int in = 0; in < 2; in++)
      *(f32x4*)(pp + 4 * (im * 2 + in)) = acc[im][in];
}

// fold KSPLIT partials, write C (+ mirror), per-block minmax -> scr
__global__ void __launch_bounds__(256) corr_reduce(const float* __restrict__ partials,
                                                   float* __restrict__ out,
                                                   float* __restrict__ scr){
  int bt = blockIdx.x;
  int b = bt / NTILE, tile = bt - b * NTILE;
  int ti = TI_[tile], tj = TJ_[tile];
  bool diag = (ti == tj);
  int t = threadIdx.x;
  int wv = t >> 6, ln = t & 63;
  int wm = wv & 1, wn = wv >> 1;
  int quad = ln >> 4, l16 = ln & 15;
  f32x4 acc[2][2];
  #pragma unroll
  for (int im = 0; im < 2; im++)
    #pragma unroll
    for (int in = 0; in < 2; in++){
      f32x4 a = {0.f, 0.f, 0.f, 0.f};
      #pragma unroll
      for (int ks = 0; ks < KSPLIT; ks++)
        a += *(const f32x4*)(partials + ((size_t)ks * (B_ * NTILE) + bt) * 4096
                             + t * 16 + 4 * (im * 2 + in));
      acc[im][in] = a;
    }
  float mn = INFINITY, mx = -INFINITY;
  float* ov = out + ((size_t)b * 3 + 2) * PIX;
  #pragma unroll
  for (int im = 0; im < 2; im++)
    #pragma unroll
    for (int in = 0; in < 2; in++){
      int gi0 = ti * 64 + wm * 32 + im * 16 + quad * 4;
      int gj  = tj * 64 + wn * 32 + in * 16 + l16;
      #pragma unroll
      for (int rg = 0; rg < 4; rg++){
        int gi = gi0 + rg;
        if (gi < IMG && gj < IMG){
          float v = acc[im][in][rg];
          ov[gi * IMG + gj] = v;
          mn = fminf(mn, v); mx = fmaxf(mx, v);
        }
      }
      if (!diag && gj < IMG && gi0 < IMG){   // mirrored tile, packed store
        float4 tv;
        tv.x = acc[im][in][0]; tv.y = acc[im][in][1];
        tv.z = acc[im][in][2]; tv.w = acc[im][in][3];
        *(float4*)(ov + gj * IMG + gi0) = tv;
      }
    }
  #pragma unroll
  for (int o = 32; o; o >>= 1){
    mn = fminf(mn, __shfl_down(mn, o)); mx = fmaxf(mx, __shfl_down(mx, o));
  }
  __shared__ float red[4][2];
  if (ln == 0){ red[wv][0] = mn; red[wv][1] = mx; }
  __syncthreads();
  if (t == 0){
    scr[bt * 2 + 0] = fminf(fminf(red[0][0], red[1][0]), fminf(red[2][0], red[3][0]));
    scr[bt * 2 + 1] = fmaxf(fmaxf(red[0][1], red[1][1]), fmaxf(red[2][1], red[3][1]));
  }
}

// ---------------- final minmax reduce + normalize --------------------------
__global__ void __launch_bounds__(256) reduce_slots(const float* __restrict__ sv_scr,
                                                    const float* __restrict__ corr_scr,
                                                    float* __restrict__ slots){
  int t = threadIdx.x;
  float tmn = sv_scr[4*t+0], tmx = sv_scr[4*t+1];
  float smn = sv_scr[4*t+2], smx = sv_scr[4*t+3];
  float cmn = INFINITY, cmx = -INFINITY;
  for (int idx = t; idx < B_ * NTILE; idx += 256){
    cmn = fminf(cmn, corr_scr[2*idx]);
    cmx = fmaxf(cmx, corr_scr[2*idx+1]);
  }
  #pragma unroll
  for (int o = 32; o; o >>= 1){
    tmn = fminf(tmn, __shfl_down(tmn, o)); tmx = fmaxf(tmx, __shfl_down(tmx, o));
    smn = fminf(smn, __shfl_down(smn, o)); smx = fmaxf(smx, __shfl_down(smx, o));
    cmn = fminf(cmn, __shfl_down(cmn, o)); cmx = fmaxf(cmx, __shfl_down(cmx, o));
  }
  __shared__ float red[4][6];
  int wv = t >> 6, ln = t & 63;
  if (ln == 0){
    red[wv][0]=tmn; red[wv][1]=tmx; red[wv][2]=smn;
    red[wv][3]=smx; red[wv][4]=cmn; red[wv][5]=cmx;
  }
  __syncthreads();
  if (t == 0){
    slots[0] = fminf(fminf(red[0][0],red[1][0]), fminf(red[2][0],red[3][0]));
    slots[1] = fmaxf(fmaxf(red[0][1],red[1][1]), fmaxf(red[2][1],red[3][1]));
    slots[2] = fminf(fminf(red[0][2],red[1][2]), fminf(red[2][2],red[3][2]));
    slots[3] = fmaxf(fmaxf(red[0][3],red[1][3]), fmaxf(red[2][3],red[3][3]));
    slots[4] = fminf(fminf(red[0][4],red[1][4]), fminf(red[2][4],red[3][4]));
    slots[5] = fmaxf(fmaxf(red[0][5],red[1][5]), fmaxf(red[2][5],red[3][5]));
  }
}

__global__ void __launch_bounds__(256) normalize_k(float* __restrict__ out,
                                                   const float* __restrict__ slots){
  int g = blockIdx.x * 256 + threadIdx.x;
  if (g >= B_ * 3 * PIX) return;
  int view = (g / PIX) % 3;  // uniform per block (PIX % 256 == 0)
  float mn = slots[2 * view];
  float mx = slots[2 * view + 1];
  float d = mx - mn;
  float v = out[g];
  out[g] = (d < 1e-8f) ? 0.f : (v - mn) / (d + 1e-8f);
}

extern "C" void kernel_launch(void* const* d_in, const int* in_sizes, int n_in,
                              void* d_out, int out_size, void* d_ws, size_t ws_size,
                              hipStream_t stream){
  const float* x = (const float*)d_in[0];
  float* out = (float*)d_out;
  char* ws = (char*)d_ws;
  float* slots    = (float*)(ws + 0);                     // 6 f (pad 256 B)
  float* meanv    = (float*)(ws + 256);                   // B*E f
  float* colmean  = meanv + B_ * E_;                      // B*N f
  float* colpart  = colmean + B_ * N_;                    // B*32*N f (16 MB)
  float* sv_scr   = colpart + (size_t)B_ * NCHUNK * N_;   // SV_BLOCKS*4 f
  float* corr_scr = sv_scr + SV_BLOCKS * 4;               // 640 f
  size_t y_off = ((size_t)((char*)(corr_scr + B_ * NTILE * 2) - ws) + 255) & ~(size_t)255;
  ushort* y = (ushort*)(ws + y_off);                      // B*224*4096 bf16 (58.7 MB)
  size_t p_off = (y_off + (size_t)B_ * IMG * N_ * 2 + 255) & ~(size_t)255;
  float* partials = (float*)(ws + p_off);                 // KSPLIT*B*NTILE*4096 f (21 MB)

  hipLaunchKernelGGL(stats_y, dim3(B_ * NCHUNK), dim3(256), 0, stream,
                     x, meanv, colpart, y);
  hipLaunchKernelGGL(corr_gemm_sk, dim3(KSPLIT * B_ * NTILE), dim3(256), 0, stream,
                     y, partials);
  hipLaunchKernelGGL(corr_reduce, dim3(B_ * NTILE), dim3(256), 0, stream,
                     partials, out, corr_scr);
  hipLaunchKernelGGL(col_finalize, dim3(B_ * 16), dim3(256), 0, stream,
                     colpart, colmean);
  hipLaunchKernelGGL(small_views, dim3(SV_BLOCKS), dim3(256), 0, stream,
                     meanv, colmean, out, sv_scr);
  hipLaunchKernelGGL(reduce_slots, dim3(1), dim3(256), 0, stream,
                     sv_scr, corr_scr, slots);
  hipLaunchKernelGGL(normalize_k, dim3((B_ * 3 * PIX + 255) / 256), dim3(256), 0, stream,
                     out, slots);
}